// Round 32
// baseline (153.510 us; speedup 1.0000x reference)
//
#include <hip/hip_runtime.h>
#include <hip/hip_fp16.h>
#include <cmath>

constexpr int NN   = 100000;
constexpr int NE   = 3200000;
constexpr int DIN  = 128;
constexpr int DH   = 32;
constexpr int DOUT = 20;

constexpr int NB    = 392;                 // coarse buckets: dst>>8 -> 0..390 (+1 pad)
constexpr int NBUSE = (NN + 255) / 256;    // 391 buckets actually used
constexpr int NBLK  = 256;                 // scatter blocks
constexpr int SLICE = NE / NBLK;           // 12500 edges per block (exact)
constexpr int BSTRIDE = 10240;             // per-bucket region (mean 8192, 22 sigma)

constexpr int NPB = 64;                    // nodes per lin1 block
constexpr int XSB = 136;                   // bf16 LDS row stride (16B-aligned, 2-way banks)
constexpr int HSS = 36;                    // fused hs row stride (16B-aligned)

typedef __attribute__((ext_vector_type(8))) short short8v;   // 8 bf16 (4 VGPRs)
typedef __attribute__((ext_vector_type(4))) float f32x4;     // MFMA accumulator

__device__ inline unsigned short f2bf(float f) {           // RNE float->bf16
    unsigned u = __builtin_bit_cast(unsigned, f);
    unsigned r = 0x7FFFu + ((u >> 16) & 1u);
    return (unsigned short)((u + r) >> 16);
}

// ---- manual fp8 e4m3fn codec (extended-low: e=0 decodes as 2^-7*(1+m/8)) ----
__device__ inline unsigned f2fp8(float f) {                // RNE float->fp8 byte
    unsigned u = __builtin_bit_cast(unsigned, f);
    unsigned s = (u >> 24) & 0x80u;
    unsigned au = u & 0x7fffffffu;
    if (au > 0x43E00000u) au = 0x43E00000u;                // clamp to 448
    unsigned u2 = au + 0x7FFFFu + ((au >> 20) & 1u);       // RNE on dropped 20 bits
    int em = (int)(u2 >> 20) - (120 << 3);                 // (E-120)<<3 | m
    em = em < 0 ? 0 : (em > 0x7E ? 0x7E : em);
    return s | (unsigned)em;
}
__device__ inline float dec8(unsigned b) {                 // fp8 byte -> float
    unsigned r = ((b & 0x80u) << 24) | (((b & 0x7fu) << 20) + 0x3C000000u);
    return __builtin_bit_cast(float, r);
}

// ------------- layer-1 projections via MFMA: xl(fp8)=x@W1l, xr(f32)=x@W1r -------------
// blocks 0/1 init bucket cursors; blocks 2/3 convert W2l/W2r to f16 (stream-ordered
// before scatterR / fused1 by kernel boundaries).
__global__ __launch_bounds__(256, 4) void lin1_kernel(
    const float* __restrict__ x, const float* __restrict__ Wl,
    const float* __restrict__ Wr, unsigned char* __restrict__ xlf8,
    float* __restrict__ xr, int* __restrict__ gcur,
    const float* __restrict__ W2l, const float* __restrict__ W2r,
    __half* __restrict__ w2h)
{
    __shared__ unsigned short xs[NPB * XSB];   // 17408 B
    int t = threadIdx.x;
    if (blockIdx.x < 2) {
        int i = blockIdx.x * 256 + t;
        if (i < NB) gcur[i] = i * BSTRIDE;
    } else if (blockIdx.x == 2) {
        for (int i = t; i < 1024; i += 256) w2h[i] = __float2half(W2l[i]);
    } else if (blockIdx.x == 3) {
        for (int i = t; i < 1024; i += 256) w2h[1024 + i] = __float2half(W2r[i]);
    }
    int nodeBase = blockIdx.x * NPB;

    const float4* x4 = reinterpret_cast<const float4*>(x) + (size_t)nodeBase * (DIN / 4);
    for (int i = t; i < NPB * (DIN / 4); i += 256) {
        int n = i >> 5, c = i & 31;
        float4 v = make_float4(0.f, 0.f, 0.f, 0.f);
        if (nodeBase + n < NN) v = x4[i];
        unsigned lo = (unsigned)f2bf(v.x) | ((unsigned)f2bf(v.y) << 16);
        unsigned hi = (unsigned)f2bf(v.z) | ((unsigned)f2bf(v.w) << 16);
        *reinterpret_cast<uint2*>(&xs[n * XSB + c * 4]) = make_uint2(lo, hi);
    }
    __syncthreads();

    int wv   = t >> 6;                 // 0..3
    int lane = t & 63;
    const float* W = (wv & 2) ? Wr : Wl;
    int jbase = (wv & 1) * 16;
    int ncol  = jbase + (lane & 15);   // B: col = lane&15
    int krow  = (lane >> 4) * 8;       // B/A: k-chunk = (lane>>4)*8

    short8v bfrag[4];
#pragma unroll
    for (int ks = 0; ks < 4; ++ks) {
        const float* wp = W + (ks * 32 + krow) * DH + ncol;
        short8v f;
#pragma unroll
        for (int e = 0; e < 8; ++e) f[e] = (short)f2bf(wp[e * DH]);
        bfrag[ks] = f;
    }

    f32x4 acc[4];
#pragma unroll
    for (int m = 0; m < 4; ++m) acc[m] = f32x4{0.f, 0.f, 0.f, 0.f};

#pragma unroll
    for (int m = 0; m < 4; ++m) {
        int row = m * 16 + (lane & 15);
#pragma unroll
        for (int ks = 0; ks < 4; ++ks) {
            short8v a = *reinterpret_cast<const short8v*>(&xs[row * XSB + ks * 32 + krow]);
            acc[m] = __builtin_amdgcn_mfma_f32_16x16x32_bf16(a, bfrag[ks], acc[m], 0, 0, 0);
        }
    }

#pragma unroll
    for (int m = 0; m < 4; ++m) {
        int rbase = m * 16 + (lane >> 4) * 4;
#pragma unroll
        for (int r = 0; r < 4; ++r) {
            int node = nodeBase + rbase + r;
            if (node < NN) {
                float v = acc[m][r];
                if (wv & 2) xr[(size_t)node * DH + ncol] = v;
                else        xlf8[(size_t)node * DH + ncol] = (unsigned char)f2fp8(v);
            }
        }
    }
}

// ------- reservation multisplit: LDS count -> reserve region -> scatter -------
// Pass-1 dst values are register-cached (13/thread) so pass 2 reads only src.
__global__ __launch_bounds__(1024) void scatterR_kernel(
    const int* __restrict__ ei, int* __restrict__ gcur,
    unsigned* __restrict__ csrtmp)
{
    __shared__ int cnt[NB];
    __shared__ int wb[NB];
    int blk = blockIdx.x, t = threadIdx.x;
    for (int i = t; i < NB; i += 1024) cnt[i] = 0;
    __syncthreads();
    int base = blk * SLICE;
    int dreg[13];
#pragma unroll
    for (int j = 0; j < 13; ++j) {
        int k = t + j * 1024;
        if (k < SLICE) {
            dreg[j] = ei[NE + base + k];
            atomicAdd(&cnt[dreg[j] >> 8], 1);                // pass 1: count
        }
    }
    __syncthreads();
    for (int i = t; i < NB; i += 1024) {
        int n = cnt[i];
        wb[i] = n ? atomicAdd(&gcur[i], n) : 0;              // reserve region
        cnt[i] = 0;                                          // reuse as cursor
    }
    __syncthreads();
#pragma unroll
    for (int j = 0; j < 13; ++j) {                           // pass 2: scatter
        int k = t + j * 1024;
        if (k < SLICE) {
            int dst = dreg[j];
            int src = ei[base + k];
            int b = dst >> 8;
            int r = atomicAdd(&cnt[b], 1);                   // LDS atomic
            csrtmp[wb[b] + r] = ((unsigned)(dst & 255) << 17) | (unsigned)src;
        }
    }
}

// ------- regroup within bucket -> csrsrc (gapped layout) + start + deg -------
// csrtmp words register-cached (<=10/thread): single global read per word.
__global__ __launch_bounds__(1024) void regroupD_kernel(
    const unsigned* __restrict__ csrtmp, const int* __restrict__ gcur,
    int* __restrict__ csrsrc, int* __restrict__ start, int* __restrict__ deg)
{
    __shared__ int h[256];
    __shared__ int sdata[256];
    int b = blockIdx.x, t = threadIdx.x;
    int lo = b * BSTRIDE, hi = gcur[b];
    if (t < 256) h[t] = 0;
    __syncthreads();
    unsigned ureg[10];
#pragma unroll
    for (int j = 0; j < 10; ++j) {
        int i = lo + t + j * 1024;
        if (i < hi) {
            ureg[j] = csrtmp[i];
            atomicAdd(&h[ureg[j] >> 17], 1);
        }
    }
    __syncthreads();
    int v = 0;
    if (t < 256) { v = h[t]; sdata[t] = v; }
    __syncthreads();
    for (int off = 1; off < 256; off <<= 1) {
        int tmp = 0;
        if (t < 256 && t >= off) tmp = sdata[t - off];
        __syncthreads();
        if (t < 256) sdata[t] += tmp;
        __syncthreads();
    }
    if (t < 256) {
        int ex = sdata[t] - v;
        int node = b * 256 + t;
        if (node < NN) { start[node] = lo + ex; deg[node] = v; }
        h[t] = ex;
    }
    __syncthreads();
#pragma unroll
    for (int j = 0; j < 10; ++j) {
        int i = lo + t + j * 1024;
        if (i < hi) {
            unsigned u = ureg[j];
            int r = atomicAdd(&h[u >> 17], 1);   // LDS atomic
            csrsrc[lo + r] = (int)(u & 0x1FFFFu);
        }
    }
}

// ===== gather core: 8 lanes/node, fp8 rows, packed-f16 accumulate =====
// Lane c loads ONE index per iteration; all 8 distributed via group shfl.
// Clamped-tail with exact correction.
__device__ inline float4 gather_core(const int* __restrict__ csrsrc,
                                     const unsigned* __restrict__ feat8,
                                     int s, int e, unsigned c)
{
    __half2 zero2 = __float2half2_rn(0.f);
    __half2 p0a = zero2, p0b = zero2, p1a = zero2, p1b = zero2;
    __half2 p2a = zero2, p2b = zero2, p3a = zero2, p3b = zero2;
    float4 corr = make_float4(0.f, 0.f, 0.f, 0.f);
    for (int i = s; i < e; i += 8) {
        int idx = i + (int)c;
        idx = idx < e ? idx : e - 1;               // clamp own lane's index
        int myIdx = csrsrc[idx];                   // 1 load per lane
        unsigned off[8];
#pragma unroll
        for (int q = 0; q < 8; ++q)
            off[q] = (unsigned)__shfl(myIdx, q, 8) * 8u + c;
        unsigned vv[8];
#pragma unroll
        for (int q = 0; q < 8; ++q) vv[q] = feat8[off[q]];
#pragma unroll
        for (int q = 0; q < 8; ++q) {
            unsigned w = vv[q];
            unsigned p01 = __builtin_amdgcn_perm(0u, w, 0x04010400u);
            unsigned p23 = __builtin_amdgcn_perm(0u, w, 0x04030402u);
            unsigned h01 = (p01 << 7) + ((p01 & 0x00800080u) << 7) + 0x20002000u;
            unsigned h23 = (p23 << 7) + ((p23 & 0x00800080u) << 7) + 0x20002000u;
            __half2 a01 = __builtin_bit_cast(__half2, h01);
            __half2 a23 = __builtin_bit_cast(__half2, h23);
            if ((q & 3) == 0) { p0a = __hadd2(p0a, a01); p0b = __hadd2(p0b, a23); }
            if ((q & 3) == 1) { p1a = __hadd2(p1a, a01); p1b = __hadd2(p1b, a23); }
            if ((q & 3) == 2) { p2a = __hadd2(p2a, a01); p2b = __hadd2(p2b, a23); }
            if ((q & 3) == 3) { p3a = __hadd2(p3a, a01); p3b = __hadd2(p3b, a23); }
        }
        if (i + 8 > e) {                           // final partial: exact correction
            float k = (float)(i + 8 - e);          // duplicates of csrsrc[e-1]
            unsigned w = vv[7];                    // q=7 is always clamped here
            corr.x = k * dec8(w & 0xFFu);
            corr.y = k * dec8((w >> 8) & 0xFFu);
            corr.z = k * dec8((w >> 16) & 0xFFu);
            corr.w = k * dec8(w >> 24);
        }
    }
    float2 f0a = __half22float2(p0a), f1a = __half22float2(p1a);
    float2 f2a = __half22float2(p2a), f3a = __half22float2(p3a);
    float2 f0b = __half22float2(p0b), f1b = __half22float2(p1b);
    float2 f2b = __half22float2(p2b), f3b = __half22float2(p3b);
    float4 r;
    r.x = f0a.x + f1a.x + f2a.x + f3a.x - corr.x;
    r.y = f0a.y + f1a.y + f2a.y + f3a.y - corr.y;
    r.z = f0b.x + f1b.x + f2b.x + f3b.x - corr.z;
    r.w = f0b.y + f1b.y + f2b.y + f3b.y - corr.w;
    return r;
}

// ===== fused layer 1 (sequential nodes, no block barrier, f16 GEMM tail) =====
__global__ __launch_bounds__(256) void fused1_kernel(
    const int* __restrict__ start, const int* __restrict__ deg,
    const int* __restrict__ csrsrc, const unsigned* __restrict__ feat8,
    const float* __restrict__ xr, const float* __restrict__ b1,
    const __half* __restrict__ w2h, unsigned* __restrict__ hlf8u,
    float* __restrict__ hr)
{
    __shared__ float hs[32][HSS];
    int tid = blockIdx.x * 256 + threadIdx.x;   // grid exact: NN*8 threads
    int g = tid >> 3;
    unsigned c = threadIdx.x & 7;
    int nl = threadIdx.x >> 3;                  // 0..31

    int s = start[g];
    int dg = deg[g];
    int e = s + dg;
    float4 r = gather_core(csrsrc, feat8, s, e, c);

    float inv = 1.0f / fmaxf((float)dg, 1.0f);
    const float4 root = *reinterpret_cast<const float4*>(xr + (size_t)g * DH + c * 4);
    const float4 bb   = *reinterpret_cast<const float4*>(b1 + c * 4);
    float4 o;
    o.x = fmaf(r.x, inv, bb.x + root.x);
    o.y = fmaf(r.y, inv, bb.y + root.y);
    o.z = fmaf(r.z, inv, bb.z + root.z);
    o.w = fmaf(r.w, inv, bb.w + root.w);

    float ss = o.x*o.x + o.y*o.y + o.z*o.z + o.w*o.w;
    ss += __shfl_xor(ss, 1);
    ss += __shfl_xor(ss, 2);
    ss += __shfl_xor(ss, 4);
    float rn = 1.0f / fmaxf(sqrtf(ss), 1e-12f);
    float4 h;
    h.x = tanhf(o.x * rn); h.y = tanhf(o.y * rn);
    h.z = tanhf(o.z * rn); h.w = tanhf(o.w * rn);
    *reinterpret_cast<float4*>(&hs[nl][c * 4]) = h;
    // no __syncthreads: hs[nl] written/read only by this 8-lane group (same wave)

    // merged f16 GEMM tail: al = h@W2l, ar = h@W2r (columns c*4..c*4+3)
    __half2 zero2 = __float2half2_rn(0.f);
    __half2 al2[2] = {zero2, zero2};
    __half2 ar2[2] = {zero2, zero2};
    const __half2* wl2 = reinterpret_cast<const __half2*>(w2h) + c * 2;        // W2l
    const __half2* wr2 = reinterpret_cast<const __half2*>(w2h) + 512 + c * 2;  // W2r
#pragma unroll
    for (int k4 = 0; k4 < 8; ++k4) {
        float4 hv = *reinterpret_cast<const float4*>(&hs[nl][k4 * 4]);
        float hk[4] = {hv.x, hv.y, hv.z, hv.w};
#pragma unroll
        for (int kk = 0; kk < 4; ++kk) {
            int k = k4 * 4 + kk;
            __half2 h2 = __float2half2_rn(hk[kk]);
            __half2 wl0 = wl2[k * 16 + 0], wl1 = wl2[k * 16 + 1];
            __half2 wr0 = wr2[k * 16 + 0], wr1 = wr2[k * 16 + 1];
            al2[0] = __hfma2(h2, wl0, al2[0]);
            al2[1] = __hfma2(h2, wl1, al2[1]);
            ar2[0] = __hfma2(h2, wr0, ar2[0]);
            ar2[1] = __hfma2(h2, wr1, ar2[1]);
        }
    }
    float al[4] = {__low2float(al2[0]), __high2float(al2[0]),
                   __low2float(al2[1]), __high2float(al2[1])};
    float ar[4] = {__low2float(ar2[0]), __high2float(ar2[0]),
                   __low2float(ar2[1]), __high2float(ar2[1])};
    hlf8u[(size_t)g * 8 + c] = f2fp8(al[0]) | (f2fp8(al[1]) << 8) |
                               (f2fp8(al[2]) << 16) | (f2fp8(al[3]) << 24);
    *reinterpret_cast<float4*>(hr + (size_t)g * DH + c * 4) =
        make_float4(ar[0], ar[1], ar[2], ar[3]);
}

// ===== fused layer 2 (sequential nodes, no block barrier) =====
__global__ __launch_bounds__(256) void fused2_kernel(
    const int* __restrict__ start, const int* __restrict__ deg,
    const int* __restrict__ csrsrc, const unsigned* __restrict__ feat8,
    const float* __restrict__ hr, const float* __restrict__ b2,
    const float* __restrict__ Wc, const float* __restrict__ bc,
    float* __restrict__ h2out, float* __restrict__ outp)
{
    __shared__ float hs[32][HSS];
    int tid = blockIdx.x * 256 + threadIdx.x;
    int g = tid >> 3;
    unsigned c = threadIdx.x & 7;
    int nl = threadIdx.x >> 3;

    int s = start[g];
    int dg = deg[g];
    int e = s + dg;
    float4 r = gather_core(csrsrc, feat8, s, e, c);

    float inv = 1.0f / fmaxf((float)dg, 1.0f);
    const float4 root = *reinterpret_cast<const float4*>(hr + (size_t)g * DH + c * 4);
    const float4 bb   = *reinterpret_cast<const float4*>(b2 + c * 4);
    float4 o;
    o.x = fmaf(r.x, inv, bb.x + root.x);
    o.y = fmaf(r.y, inv, bb.y + root.y);
    o.z = fmaf(r.z, inv, bb.z + root.z);
    o.w = fmaf(r.w, inv, bb.w + root.w);

    float ss = o.x*o.x + o.y*o.y + o.z*o.z + o.w*o.w;
    ss += __shfl_xor(ss, 1);
    ss += __shfl_xor(ss, 2);
    ss += __shfl_xor(ss, 4);
    float rn = 1.0f / fmaxf(sqrtf(ss), 1e-12f);
    float4 h;
    h.x = tanhf(o.x * rn); h.y = tanhf(o.y * rn);
    h.z = tanhf(o.z * rn); h.w = tanhf(o.w * rn);
    *reinterpret_cast<float4*>(&hs[nl][c * 4]) = h;
    *reinterpret_cast<float4*>(h2out + (size_t)g * DH + c * 4) = h;
    // no __syncthreads: group-local LDS row, same wave

    // classifier: lanes 0-3 of each 8-lane group compute 5 logits each
    if (c < 4) {
        float z[5];
#pragma unroll
        for (int q = 0; q < 5; ++q) z[q] = bc[c * 5 + q];
#pragma unroll
        for (int k4 = 0; k4 < 8; ++k4) {
            float4 hv = *reinterpret_cast<const float4*>(&hs[nl][k4 * 4]);
            float hk[4] = {hv.x, hv.y, hv.z, hv.w};
#pragma unroll
            for (int kk = 0; kk < 4; ++kk) {
                const float* wc = Wc + (k4*4+kk) * DOUT + c * 5;
#pragma unroll
                for (int q = 0; q < 5; ++q) z[q] = fmaf(hk[kk], wc[q], z[q]);
            }
        }
        float m = z[0];
#pragma unroll
        for (int q = 1; q < 5; ++q) m = fmaxf(m, z[q]);
        m = fmaxf(m, __shfl_xor(m, 1));
        m = fmaxf(m, __shfl_xor(m, 2));
        float sum = 0.f;
#pragma unroll
        for (int q = 0; q < 5; ++q) sum += expf(z[q] - m);
        sum += __shfl_xor(sum, 1);
        sum += __shfl_xor(sum, 2);
        float lse = m + logf(sum);
        float* orow = outp + (size_t)g * DOUT + c * 5;
#pragma unroll
        for (int q = 0; q < 5; ++q) orow[q] = z[q] - lse;
    }
}

extern "C" void kernel_launch(void* const* d_in, const int* in_sizes, int n_in,
                              void* d_out, int out_size, void* d_ws, size_t ws_size,
                              hipStream_t stream) {
    const float* x   = (const float*)d_in[0];
    const int*   ei  = (const int*)d_in[1];
    const float* W1l = (const float*)d_in[2];
    const float* b1  = (const float*)d_in[3];
    const float* W1r = (const float*)d_in[4];
    const float* W2l = (const float*)d_in[5];
    const float* b2  = (const float*)d_in[6];
    const float* W2r = (const float*)d_in[7];
    const float* Wc  = (const float*)d_in[8];
    const float* bc  = (const float*)d_in[9];

    float* outp = (float*)d_out;                          // [NN, 20]
    float* hout = outp + (size_t)NN * DOUT;               // [NN, 32]

    // workspace layout
    unsigned char* xlf8 = (unsigned char*)d_ws;           // NN*DH fp8 (3.2 MB)
    unsigned char* hlf8 = xlf8 + (size_t)NN * DH;         // NN*DH fp8 (3.2 MB)
    float* xr      = (float*)(hlf8 + (size_t)NN * DH);    // NN*DH f32 (also hr, node-local)
    unsigned* csrtmp = (unsigned*)(xr + (size_t)NN * DH); // NB*BSTRIDE u32 (gapped)
    int* csrsrc    = (int*)(csrtmp + (size_t)NB * BSTRIDE); // NB*BSTRIDE (gapped)
    int* start     = csrsrc + (size_t)NB * BSTRIDE;       // NN
    int* deg       = start + NN;                          // NN
    int* gcur      = deg + NN;                            // NB
    __half* w2h    = (__half*)(gcur + NB);                // 2048 halves (8B-aligned)

    const int lin1Blocks  = (NN + NPB - 1) / NPB;         // 1563
    const int fusedBlocks = (NN * 8) / 256;               // 3125 exact

    lin1_kernel<<<lin1Blocks, 256, 0, stream>>>(x, W1l, W1r, xlf8, xr, gcur,
                                                W2l, W2r, w2h);

    scatterR_kernel<<<NBLK, 1024, 0, stream>>>(ei, gcur, csrtmp);
    regroupD_kernel<<<NBUSE, 1024, 0, stream>>>(csrtmp, gcur, csrsrc, start, deg);

    fused1_kernel<<<fusedBlocks, 256, 0, stream>>>(start, deg, csrsrc,
        (const unsigned*)xlf8, xr, b1, w2h, (unsigned*)hlf8, xr);

    fused2_kernel<<<fusedBlocks, 256, 0, stream>>>(start, deg, csrsrc,
        (const unsigned*)hlf8, xr, b2, Wc, bc, hout, outp);
}

// Round 33
// 151.390 us; speedup vs baseline: 1.0140x; 1.0140x over previous
//
#include <hip/hip_runtime.h>
#include <hip/hip_fp16.h>
#include <cmath>

constexpr int NN   = 100000;
constexpr int NE   = 3200000;
constexpr int DIN  = 128;
constexpr int DH   = 32;
constexpr int DOUT = 20;

constexpr int NB    = 392;                 // coarse buckets: dst>>8 -> 0..390 (+1 pad)
constexpr int NBUSE = (NN + 255) / 256;    // 391 buckets actually used
constexpr int NBLK  = 256;                 // scatter blocks
constexpr int SLICE = NE / NBLK;           // 12500 edges per block (exact)
constexpr int BSTRIDE = 10240;             // per-bucket region (mean 8192, 22 sigma)

constexpr int NPB = 64;                    // nodes per lin1 block
constexpr int XSB = 136;                   // bf16 LDS row stride (16B-aligned, 2-way banks)
constexpr int HSS = 36;                    // fused hs row stride (16B-aligned)

typedef __attribute__((ext_vector_type(8))) short short8v;   // 8 bf16 (4 VGPRs)
typedef __attribute__((ext_vector_type(4))) float f32x4;     // MFMA accumulator

__device__ inline unsigned short f2bf(float f) {           // RNE float->bf16
    unsigned u = __builtin_bit_cast(unsigned, f);
    unsigned r = 0x7FFFu + ((u >> 16) & 1u);
    return (unsigned short)((u + r) >> 16);
}

// ---- manual fp8 e4m3fn codec (extended-low: e=0 decodes as 2^-7*(1+m/8)) ----
__device__ inline unsigned f2fp8(float f) {                // RNE float->fp8 byte
    unsigned u = __builtin_bit_cast(unsigned, f);
    unsigned s = (u >> 24) & 0x80u;
    unsigned au = u & 0x7fffffffu;
    if (au > 0x43E00000u) au = 0x43E00000u;                // clamp to 448
    unsigned u2 = au + 0x7FFFFu + ((au >> 20) & 1u);       // RNE on dropped 20 bits
    int em = (int)(u2 >> 20) - (120 << 3);                 // (E-120)<<3 | m
    em = em < 0 ? 0 : (em > 0x7E ? 0x7E : em);
    return s | (unsigned)em;
}
__device__ inline float dec8(unsigned b) {                 // fp8 byte -> float
    unsigned r = ((b & 0x80u) << 24) | (((b & 0x7fu) << 20) + 0x3C000000u);
    return __builtin_bit_cast(float, r);
}

// ------------- layer-1 projections via MFMA: xl(fp8)=x@W1l, xr(f32)=x@W1r -------------
// blocks 0/1 additionally initialize the bucket cursors (ordered before scatterR
// by the kernel boundary on the stream).
__global__ __launch_bounds__(256, 4) void lin1_kernel(
    const float* __restrict__ x, const float* __restrict__ Wl,
    const float* __restrict__ Wr, unsigned char* __restrict__ xlf8,
    float* __restrict__ xr, int* __restrict__ gcur)
{
    __shared__ unsigned short xs[NPB * XSB];   // 17408 B
    int t = threadIdx.x;
    if (blockIdx.x < 2) {
        int i = blockIdx.x * 256 + t;
        if (i < NB) gcur[i] = i * BSTRIDE;
    }
    int nodeBase = blockIdx.x * NPB;

    const float4* x4 = reinterpret_cast<const float4*>(x) + (size_t)nodeBase * (DIN / 4);
    for (int i = t; i < NPB * (DIN / 4); i += 256) {
        int n = i >> 5, c = i & 31;
        float4 v = make_float4(0.f, 0.f, 0.f, 0.f);
        if (nodeBase + n < NN) v = x4[i];
        unsigned lo = (unsigned)f2bf(v.x) | ((unsigned)f2bf(v.y) << 16);
        unsigned hi = (unsigned)f2bf(v.z) | ((unsigned)f2bf(v.w) << 16);
        *reinterpret_cast<uint2*>(&xs[n * XSB + c * 4]) = make_uint2(lo, hi);
    }
    __syncthreads();

    int wv   = t >> 6;                 // 0..3
    int lane = t & 63;
    const float* W = (wv & 2) ? Wr : Wl;
    int jbase = (wv & 1) * 16;
    int ncol  = jbase + (lane & 15);   // B: col = lane&15
    int krow  = (lane >> 4) * 8;       // B/A: k-chunk = (lane>>4)*8

    short8v bfrag[4];
#pragma unroll
    for (int ks = 0; ks < 4; ++ks) {
        const float* wp = W + (ks * 32 + krow) * DH + ncol;
        short8v f;
#pragma unroll
        for (int e = 0; e < 8; ++e) f[e] = (short)f2bf(wp[e * DH]);
        bfrag[ks] = f;
    }

    f32x4 acc[4];
#pragma unroll
    for (int m = 0; m < 4; ++m) acc[m] = f32x4{0.f, 0.f, 0.f, 0.f};

#pragma unroll
    for (int m = 0; m < 4; ++m) {
        int row = m * 16 + (lane & 15);
#pragma unroll
        for (int ks = 0; ks < 4; ++ks) {
            short8v a = *reinterpret_cast<const short8v*>(&xs[row * XSB + ks * 32 + krow]);
            acc[m] = __builtin_amdgcn_mfma_f32_16x16x32_bf16(a, bfrag[ks], acc[m], 0, 0, 0);
        }
    }

#pragma unroll
    for (int m = 0; m < 4; ++m) {
        int rbase = m * 16 + (lane >> 4) * 4;
#pragma unroll
        for (int r = 0; r < 4; ++r) {
            int node = nodeBase + rbase + r;
            if (node < NN) {
                float v = acc[m][r];
                if (wv & 2) xr[(size_t)node * DH + ncol] = v;
                else        xlf8[(size_t)node * DH + ncol] = (unsigned char)f2fp8(v);
            }
        }
    }
}

// ------- reservation multisplit: LDS count -> reserve region -> scatter -------
// Pass-1 dst values are register-cached (13/thread) so pass 2 reads only src.
__global__ __launch_bounds__(1024) void scatterR_kernel(
    const int* __restrict__ ei, int* __restrict__ gcur,
    unsigned* __restrict__ csrtmp)
{
    __shared__ int cnt[NB];
    __shared__ int wb[NB];
    int blk = blockIdx.x, t = threadIdx.x;
    for (int i = t; i < NB; i += 1024) cnt[i] = 0;
    __syncthreads();
    int base = blk * SLICE;
    int dreg[13];
#pragma unroll
    for (int j = 0; j < 13; ++j) {
        int k = t + j * 1024;
        if (k < SLICE) {
            dreg[j] = ei[NE + base + k];
            atomicAdd(&cnt[dreg[j] >> 8], 1);                // pass 1: count
        }
    }
    __syncthreads();
    for (int i = t; i < NB; i += 1024) {
        int n = cnt[i];
        wb[i] = n ? atomicAdd(&gcur[i], n) : 0;              // reserve region
        cnt[i] = 0;                                          // reuse as cursor
    }
    __syncthreads();
#pragma unroll
    for (int j = 0; j < 13; ++j) {                           // pass 2: scatter
        int k = t + j * 1024;
        if (k < SLICE) {
            int dst = dreg[j];
            int src = ei[base + k];
            int b = dst >> 8;
            int r = atomicAdd(&cnt[b], 1);                   // LDS atomic
            csrtmp[wb[b] + r] = ((unsigned)(dst & 255) << 17) | (unsigned)src;
        }
    }
}

// ------- regroup within bucket -> csrsrc (gapped layout) + start + deg -------
// csrtmp words register-cached (<=10/thread): single global read per word.
__global__ __launch_bounds__(1024) void regroupD_kernel(
    const unsigned* __restrict__ csrtmp, const int* __restrict__ gcur,
    int* __restrict__ csrsrc, int* __restrict__ start, int* __restrict__ deg)
{
    __shared__ int h[256];
    __shared__ int sdata[256];
    int b = blockIdx.x, t = threadIdx.x;
    int lo = b * BSTRIDE, hi = gcur[b];
    if (t < 256) h[t] = 0;
    __syncthreads();
    unsigned ureg[10];
#pragma unroll
    for (int j = 0; j < 10; ++j) {
        int i = lo + t + j * 1024;
        if (i < hi) {
            ureg[j] = csrtmp[i];
            atomicAdd(&h[ureg[j] >> 17], 1);
        }
    }
    __syncthreads();
    int v = 0;
    if (t < 256) { v = h[t]; sdata[t] = v; }
    __syncthreads();
    for (int off = 1; off < 256; off <<= 1) {
        int tmp = 0;
        if (t < 256 && t >= off) tmp = sdata[t - off];
        __syncthreads();
        if (t < 256) sdata[t] += tmp;
        __syncthreads();
    }
    if (t < 256) {
        int ex = sdata[t] - v;
        int node = b * 256 + t;
        if (node < NN) { start[node] = lo + ex; deg[node] = v; }
        h[t] = ex;
    }
    __syncthreads();
#pragma unroll
    for (int j = 0; j < 10; ++j) {
        int i = lo + t + j * 1024;
        if (i < hi) {
            unsigned u = ureg[j];
            int r = atomicAdd(&h[u >> 17], 1);   // LDS atomic
            csrsrc[lo + r] = (int)(u & 0x1FFFFu);
        }
    }
}

// ===== gather core: 8 lanes/node, fp8 rows, packed-f16 accumulate =====
// Software-pipelined index load: iteration i consumes myIdx loaded in i-1;
// the next index load issues right after the shfl so its latency hides under
// the 8 feat loads + decode. Clamp semantics identical to round 25/31.
__device__ inline float4 gather_core(const int* __restrict__ csrsrc,
                                     const unsigned* __restrict__ feat8,
                                     int s, int e, unsigned c)
{
    __half2 zero2 = __float2half2_rn(0.f);
    __half2 p0a = zero2, p0b = zero2, p1a = zero2, p1b = zero2;
    __half2 p2a = zero2, p2b = zero2, p3a = zero2, p3b = zero2;
    float4 corr = make_float4(0.f, 0.f, 0.f, 0.f);
    int idx0 = s + (int)c;
    idx0 = idx0 < e ? idx0 : e - 1;
    int myIdx = csrsrc[idx0];                      // prologue index load
    for (int i = s; i < e; i += 8) {
        unsigned off[8];
#pragma unroll
        for (int q = 0; q < 8; ++q)
            off[q] = (unsigned)__shfl(myIdx, q, 8) * 8u + c;
        int nidx = i + 8 + (int)c;                 // prefetch next iter's index
        nidx = nidx < e ? nidx : e - 1;            // clamped: always in-bounds
        int nextIdx = csrsrc[nidx];
        unsigned vv[8];
#pragma unroll
        for (int q = 0; q < 8; ++q) vv[q] = feat8[off[q]];
#pragma unroll
        for (int q = 0; q < 8; ++q) {
            unsigned w = vv[q];
            unsigned p01 = __builtin_amdgcn_perm(0u, w, 0x04010400u);
            unsigned p23 = __builtin_amdgcn_perm(0u, w, 0x04030402u);
            unsigned h01 = (p01 << 7) + ((p01 & 0x00800080u) << 7) + 0x20002000u;
            unsigned h23 = (p23 << 7) + ((p23 & 0x00800080u) << 7) + 0x20002000u;
            __half2 a01 = __builtin_bit_cast(__half2, h01);
            __half2 a23 = __builtin_bit_cast(__half2, h23);
            if ((q & 3) == 0) { p0a = __hadd2(p0a, a01); p0b = __hadd2(p0b, a23); }
            if ((q & 3) == 1) { p1a = __hadd2(p1a, a01); p1b = __hadd2(p1b, a23); }
            if ((q & 3) == 2) { p2a = __hadd2(p2a, a01); p2b = __hadd2(p2b, a23); }
            if ((q & 3) == 3) { p3a = __hadd2(p3a, a01); p3b = __hadd2(p3b, a23); }
        }
        if (i + 8 > e) {                           // final partial: exact correction
            float k = (float)(i + 8 - e);          // duplicates of csrsrc[e-1]
            unsigned w = vv[7];                    // q=7 is always clamped here
            corr.x = k * dec8(w & 0xFFu);
            corr.y = k * dec8((w >> 8) & 0xFFu);
            corr.z = k * dec8((w >> 16) & 0xFFu);
            corr.w = k * dec8(w >> 24);
        }
        myIdx = nextIdx;
    }
    float2 f0a = __half22float2(p0a), f1a = __half22float2(p1a);
    float2 f2a = __half22float2(p2a), f3a = __half22float2(p3a);
    float2 f0b = __half22float2(p0b), f1b = __half22float2(p1b);
    float2 f2b = __half22float2(p2b), f3b = __half22float2(p3b);
    float4 r;
    r.x = f0a.x + f1a.x + f2a.x + f3a.x - corr.x;
    r.y = f0a.y + f1a.y + f2a.y + f3a.y - corr.y;
    r.z = f0b.x + f1b.x + f2b.x + f3b.x - corr.z;
    r.w = f0b.y + f1b.y + f2b.y + f3b.y - corr.w;
    return r;
}

// ===== fused layer 1 (sequential nodes, no block barrier) =====
__global__ __launch_bounds__(256) void fused1_kernel(
    const int* __restrict__ start, const int* __restrict__ deg,
    const int* __restrict__ csrsrc, const unsigned* __restrict__ feat8,
    const float* __restrict__ xr, const float* __restrict__ b1,
    const float* __restrict__ W2l, const float* __restrict__ W2r,
    unsigned* __restrict__ hlf8u, float* __restrict__ hr)
{
    __shared__ float hs[32][HSS];
    int tid = blockIdx.x * 256 + threadIdx.x;   // grid exact: NN*8 threads
    int g = tid >> 3;
    unsigned c = threadIdx.x & 7;
    int nl = threadIdx.x >> 3;                  // 0..31

    int s = start[g];
    int dg = deg[g];
    int e = s + dg;
    float4 r = gather_core(csrsrc, feat8, s, e, c);

    float inv = 1.0f / fmaxf((float)dg, 1.0f);
    const float4 root = *reinterpret_cast<const float4*>(xr + (size_t)g * DH + c * 4);
    const float4 bb   = *reinterpret_cast<const float4*>(b1 + c * 4);
    float4 o;
    o.x = fmaf(r.x, inv, bb.x + root.x);
    o.y = fmaf(r.y, inv, bb.y + root.y);
    o.z = fmaf(r.z, inv, bb.z + root.z);
    o.w = fmaf(r.w, inv, bb.w + root.w);

    float ss = o.x*o.x + o.y*o.y + o.z*o.z + o.w*o.w;
    ss += __shfl_xor(ss, 1);
    ss += __shfl_xor(ss, 2);
    ss += __shfl_xor(ss, 4);
    float rn = 1.0f / fmaxf(sqrtf(ss), 1e-12f);
    float4 h;
    h.x = tanhf(o.x * rn); h.y = tanhf(o.y * rn);
    h.z = tanhf(o.z * rn); h.w = tanhf(o.w * rn);
    *reinterpret_cast<float4*>(&hs[nl][c * 4]) = h;
    // no __syncthreads: hs[nl] written/read only by this 8-lane group (same wave)

    float al[4] = {0.f, 0.f, 0.f, 0.f};
    float ar[4] = {0.f, 0.f, 0.f, 0.f};
#pragma unroll
    for (int k4 = 0; k4 < 8; ++k4) {
        float4 hv = *reinterpret_cast<const float4*>(&hs[nl][k4 * 4]);
        float hk[4] = {hv.x, hv.y, hv.z, hv.w};
#pragma unroll
        for (int kk = 0; kk < 4; ++kk) {
            const float4* wl4 = reinterpret_cast<const float4*>(W2l + (k4*4+kk) * DH + c * 4);
            const float4* wr4 = reinterpret_cast<const float4*>(W2r + (k4*4+kk) * DH + c * 4);
            float4 wl = wl4[0], wr = wr4[0];
            al[0] = fmaf(hk[kk], wl.x, al[0]);
            al[1] = fmaf(hk[kk], wl.y, al[1]);
            al[2] = fmaf(hk[kk], wl.z, al[2]);
            al[3] = fmaf(hk[kk], wl.w, al[3]);
            ar[0] = fmaf(hk[kk], wr.x, ar[0]);
            ar[1] = fmaf(hk[kk], wr.y, ar[1]);
            ar[2] = fmaf(hk[kk], wr.z, ar[2]);
            ar[3] = fmaf(hk[kk], wr.w, ar[3]);
        }
    }
    hlf8u[(size_t)g * 8 + c] = f2fp8(al[0]) | (f2fp8(al[1]) << 8) |
                               (f2fp8(al[2]) << 16) | (f2fp8(al[3]) << 24);
    *reinterpret_cast<float4*>(hr + (size_t)g * DH + c * 4) =
        make_float4(ar[0], ar[1], ar[2], ar[3]);
}

// ===== fused layer 2 (sequential nodes, no block barrier) =====
__global__ __launch_bounds__(256) void fused2_kernel(
    const int* __restrict__ start, const int* __restrict__ deg,
    const int* __restrict__ csrsrc, const unsigned* __restrict__ feat8,
    const float* __restrict__ hr, const float* __restrict__ b2,
    const float* __restrict__ Wc, const float* __restrict__ bc,
    float* __restrict__ h2out, float* __restrict__ outp)
{
    __shared__ float hs[32][HSS];
    int tid = blockIdx.x * 256 + threadIdx.x;
    int g = tid >> 3;
    unsigned c = threadIdx.x & 7;
    int nl = threadIdx.x >> 3;

    int s = start[g];
    int dg = deg[g];
    int e = s + dg;
    float4 r = gather_core(csrsrc, feat8, s, e, c);

    float inv = 1.0f / fmaxf((float)dg, 1.0f);
    const float4 root = *reinterpret_cast<const float4*>(hr + (size_t)g * DH + c * 4);
    const float4 bb   = *reinterpret_cast<const float4*>(b2 + c * 4);
    float4 o;
    o.x = fmaf(r.x, inv, bb.x + root.x);
    o.y = fmaf(r.y, inv, bb.y + root.y);
    o.z = fmaf(r.z, inv, bb.z + root.z);
    o.w = fmaf(r.w, inv, bb.w + root.w);

    float ss = o.x*o.x + o.y*o.y + o.z*o.z + o.w*o.w;
    ss += __shfl_xor(ss, 1);
    ss += __shfl_xor(ss, 2);
    ss += __shfl_xor(ss, 4);
    float rn = 1.0f / fmaxf(sqrtf(ss), 1e-12f);
    float4 h;
    h.x = tanhf(o.x * rn); h.y = tanhf(o.y * rn);
    h.z = tanhf(o.z * rn); h.w = tanhf(o.w * rn);
    *reinterpret_cast<float4*>(&hs[nl][c * 4]) = h;
    *reinterpret_cast<float4*>(h2out + (size_t)g * DH + c * 4) = h;
    // no __syncthreads: group-local LDS row, same wave

    // classifier: lanes 0-3 of each 8-lane group compute 5 logits each
    if (c < 4) {
        float z[5];
#pragma unroll
        for (int q = 0; q < 5; ++q) z[q] = bc[c * 5 + q];
#pragma unroll
        for (int k4 = 0; k4 < 8; ++k4) {
            float4 hv = *reinterpret_cast<const float4*>(&hs[nl][k4 * 4]);
            float hk[4] = {hv.x, hv.y, hv.z, hv.w};
#pragma unroll
            for (int kk = 0; kk < 4; ++kk) {
                const float* wc = Wc + (k4*4+kk) * DOUT + c * 5;
#pragma unroll
                for (int q = 0; q < 5; ++q) z[q] = fmaf(hk[kk], wc[q], z[q]);
            }
        }
        float m = z[0];
#pragma unroll
        for (int q = 1; q < 5; ++q) m = fmaxf(m, z[q]);
        m = fmaxf(m, __shfl_xor(m, 1));
        m = fmaxf(m, __shfl_xor(m, 2));
        float sum = 0.f;
#pragma unroll
        for (int q = 0; q < 5; ++q) sum += expf(z[q] - m);
        sum += __shfl_xor(sum, 1);
        sum += __shfl_xor(sum, 2);
        float lse = m + logf(sum);
        float* orow = outp + (size_t)g * DOUT + c * 5;
#pragma unroll
        for (int q = 0; q < 5; ++q) orow[q] = z[q] - lse;
    }
}

extern "C" void kernel_launch(void* const* d_in, const int* in_sizes, int n_in,
                              void* d_out, int out_size, void* d_ws, size_t ws_size,
                              hipStream_t stream) {
    const float* x   = (const float*)d_in[0];
    const int*   ei  = (const int*)d_in[1];
    const float* W1l = (const float*)d_in[2];
    const float* b1  = (const float*)d_in[3];
    const float* W1r = (const float*)d_in[4];
    const float* W2l = (const float*)d_in[5];
    const float* b2  = (const float*)d_in[6];
    const float* W2r = (const float*)d_in[7];
    const float* Wc  = (const float*)d_in[8];
    const float* bc  = (const float*)d_in[9];

    float* outp = (float*)d_out;                          // [NN, 20]
    float* hout = outp + (size_t)NN * DOUT;               // [NN, 32]

    // workspace layout
    unsigned char* xlf8 = (unsigned char*)d_ws;           // NN*DH fp8 (3.2 MB)
    unsigned char* hlf8 = xlf8 + (size_t)NN * DH;         // NN*DH fp8 (3.2 MB)
    float* xr      = (float*)(hlf8 + (size_t)NN * DH);    // NN*DH f32 (also hr, node-local)
    unsigned* csrtmp = (unsigned*)(xr + (size_t)NN * DH); // NB*BSTRIDE u32 (gapped)
    int* csrsrc    = (int*)(csrtmp + (size_t)NB * BSTRIDE); // NB*BSTRIDE (gapped)
    int* start     = csrsrc + (size_t)NB * BSTRIDE;       // NN
    int* deg       = start + NN;                          // NN
    int* gcur      = deg + NN;                            // NB

    const int lin1Blocks  = (NN + NPB - 1) / NPB;         // 1563
    const int fusedBlocks = (NN * 8) / 256;               // 3125 exact

    lin1_kernel<<<lin1Blocks, 256, 0, stream>>>(x, W1l, W1r, xlf8, xr, gcur);

    scatterR_kernel<<<NBLK, 1024, 0, stream>>>(ei, gcur, csrtmp);
    regroupD_kernel<<<NBUSE, 1024, 0, stream>>>(csrtmp, gcur, csrsrc, start, deg);

    fused1_kernel<<<fusedBlocks, 256, 0, stream>>>(start, deg, csrsrc,
        (const unsigned*)xlf8, xr, b1, W2l, W2r, (unsigned*)hlf8, xr);

    fused2_kernel<<<fusedBlocks, 256, 0, stream>>>(start, deg, csrsrc,
        (const unsigned*)hlf8, xr, b2, Wc, bc, hout, outp);
}

// Round 34
// 149.200 us; speedup vs baseline: 1.0289x; 1.0147x over previous
//
#include <hip/hip_runtime.h>
#include <hip/hip_fp16.h>
#include <cmath>

constexpr int NN   = 100000;
constexpr int NE   = 3200000;
constexpr int DIN  = 128;
constexpr int DH   = 32;
constexpr int DOUT = 20;

constexpr int NB    = 392;                 // coarse buckets: dst>>8 -> 0..390 (+1 pad)
constexpr int NBUSE = (NN + 255) / 256;    // 391 buckets actually used
constexpr int NBLK  = 256;                 // scatter blocks
constexpr int SLICE = NE / NBLK;           // 12500 edges per block (exact)
constexpr int BSTRIDE = 10240;             // per-bucket region (mean 8192, 22 sigma)

constexpr int NPB = 64;                    // nodes per lin1 block
constexpr int XSB = 136;                   // bf16 LDS row stride (16B-aligned, 2-way banks)
constexpr int HSS = 36;                    // fused hs row stride (16B-aligned)

typedef __attribute__((ext_vector_type(8))) short short8v;   // 8 bf16 (4 VGPRs)
typedef __attribute__((ext_vector_type(4))) float f32x4;     // MFMA accumulator

__device__ inline unsigned short f2bf(float f) {           // RNE float->bf16
    unsigned u = __builtin_bit_cast(unsigned, f);
    unsigned r = 0x7FFFu + ((u >> 16) & 1u);
    return (unsigned short)((u + r) >> 16);
}
__device__ inline float bflo(unsigned u) {                 // low bf16 -> float
    return __builtin_bit_cast(float, u << 16);
}
__device__ inline float bfhi(unsigned u) {                 // high bf16 -> float
    return __builtin_bit_cast(float, u & 0xFFFF0000u);
}

// ---- manual fp8 e4m3fn codec (extended-low: e=0 decodes as 2^-7*(1+m/8)) ----
__device__ inline unsigned f2fp8(float f) {                // RNE float->fp8 byte
    unsigned u = __builtin_bit_cast(unsigned, f);
    unsigned s = (u >> 24) & 0x80u;
    unsigned au = u & 0x7fffffffu;
    if (au > 0x43E00000u) au = 0x43E00000u;                // clamp to 448
    unsigned u2 = au + 0x7FFFFu + ((au >> 20) & 1u);       // RNE on dropped 20 bits
    int em = (int)(u2 >> 20) - (120 << 3);                 // (E-120)<<3 | m
    em = em < 0 ? 0 : (em > 0x7E ? 0x7E : em);
    return s | (unsigned)em;
}
__device__ inline float dec8(unsigned b) {                 // fp8 byte -> float
    unsigned r = ((b & 0x80u) << 24) | (((b & 0x7fu) << 20) + 0x3C000000u);
    return __builtin_bit_cast(float, r);
}

// ------------- layer-1 projections via MFMA: xl(fp8)=x@W1l, xr(bf16)=x@W1r -------------
// blocks 0/1 additionally initialize the bucket cursors (ordered before scatterR
// by the kernel boundary on the stream).
__global__ __launch_bounds__(256, 4) void lin1_kernel(
    const float* __restrict__ x, const float* __restrict__ Wl,
    const float* __restrict__ Wr, unsigned char* __restrict__ xlf8,
    unsigned short* __restrict__ xrbf, int* __restrict__ gcur)
{
    __shared__ unsigned short xs[NPB * XSB];   // 17408 B
    int t = threadIdx.x;
    if (blockIdx.x < 2) {
        int i = blockIdx.x * 256 + t;
        if (i < NB) gcur[i] = i * BSTRIDE;
    }
    int nodeBase = blockIdx.x * NPB;

    const float4* x4 = reinterpret_cast<const float4*>(x) + (size_t)nodeBase * (DIN / 4);
    for (int i = t; i < NPB * (DIN / 4); i += 256) {
        int n = i >> 5, c = i & 31;
        float4 v = make_float4(0.f, 0.f, 0.f, 0.f);
        if (nodeBase + n < NN) v = x4[i];
        unsigned lo = (unsigned)f2bf(v.x) | ((unsigned)f2bf(v.y) << 16);
        unsigned hi = (unsigned)f2bf(v.z) | ((unsigned)f2bf(v.w) << 16);
        *reinterpret_cast<uint2*>(&xs[n * XSB + c * 4]) = make_uint2(lo, hi);
    }
    __syncthreads();

    int wv   = t >> 6;                 // 0..3
    int lane = t & 63;
    const float* W = (wv & 2) ? Wr : Wl;
    int jbase = (wv & 1) * 16;
    int ncol  = jbase + (lane & 15);   // B: col = lane&15
    int krow  = (lane >> 4) * 8;       // B/A: k-chunk = (lane>>4)*8

    short8v bfrag[4];
#pragma unroll
    for (int ks = 0; ks < 4; ++ks) {
        const float* wp = W + (ks * 32 + krow) * DH + ncol;
        short8v f;
#pragma unroll
        for (int e = 0; e < 8; ++e) f[e] = (short)f2bf(wp[e * DH]);
        bfrag[ks] = f;
    }

    f32x4 acc[4];
#pragma unroll
    for (int m = 0; m < 4; ++m) acc[m] = f32x4{0.f, 0.f, 0.f, 0.f};

#pragma unroll
    for (int m = 0; m < 4; ++m) {
        int row = m * 16 + (lane & 15);
#pragma unroll
        for (int ks = 0; ks < 4; ++ks) {
            short8v a = *reinterpret_cast<const short8v*>(&xs[row * XSB + ks * 32 + krow]);
            acc[m] = __builtin_amdgcn_mfma_f32_16x16x32_bf16(a, bfrag[ks], acc[m], 0, 0, 0);
        }
    }

#pragma unroll
    for (int m = 0; m < 4; ++m) {
        int rbase = m * 16 + (lane >> 4) * 4;
#pragma unroll
        for (int r = 0; r < 4; ++r) {
            int node = nodeBase + rbase + r;
            if (node < NN) {
                float v = acc[m][r];
                if (wv & 2) xrbf[(size_t)node * DH + ncol] = f2bf(v);
                else        xlf8[(size_t)node * DH + ncol] = (unsigned char)f2fp8(v);
            }
        }
    }
}

// ------- reservation multisplit: LDS count -> reserve region -> scatter -------
// Pass-1 dst values are register-cached (13/thread) so pass 2 reads only src.
__global__ __launch_bounds__(1024) void scatterR_kernel(
    const int* __restrict__ ei, int* __restrict__ gcur,
    unsigned* __restrict__ csrtmp)
{
    __shared__ int cnt[NB];
    __shared__ int wb[NB];
    int blk = blockIdx.x, t = threadIdx.x;
    for (int i = t; i < NB; i += 1024) cnt[i] = 0;
    __syncthreads();
    int base = blk * SLICE;
    int dreg[13];
#pragma unroll
    for (int j = 0; j < 13; ++j) {
        int k = t + j * 1024;
        if (k < SLICE) {
            dreg[j] = ei[NE + base + k];
            atomicAdd(&cnt[dreg[j] >> 8], 1);                // pass 1: count
        }
    }
    __syncthreads();
    for (int i = t; i < NB; i += 1024) {
        int n = cnt[i];
        wb[i] = n ? atomicAdd(&gcur[i], n) : 0;              // reserve region
        cnt[i] = 0;                                          // reuse as cursor
    }
    __syncthreads();
#pragma unroll
    for (int j = 0; j < 13; ++j) {                           // pass 2: scatter
        int k = t + j * 1024;
        if (k < SLICE) {
            int dst = dreg[j];
            int src = ei[base + k];
            int b = dst >> 8;
            int r = atomicAdd(&cnt[b], 1);                   // LDS atomic
            csrtmp[wb[b] + r] = ((unsigned)(dst & 255) << 17) | (unsigned)src;
        }
    }
}

// ------- regroup within bucket -> csrsrc (gapped layout) + start + deg -------
// csrtmp words register-cached (<=10/thread): single global read per word.
__global__ __launch_bounds__(1024) void regroupD_kernel(
    const unsigned* __restrict__ csrtmp, const int* __restrict__ gcur,
    int* __restrict__ csrsrc, int* __restrict__ start, int* __restrict__ deg)
{
    __shared__ int h[256];
    __shared__ int sdata[256];
    int b = blockIdx.x, t = threadIdx.x;
    int lo = b * BSTRIDE, hi = gcur[b];
    if (t < 256) h[t] = 0;
    __syncthreads();
    unsigned ureg[10];
#pragma unroll
    for (int j = 0; j < 10; ++j) {
        int i = lo + t + j * 1024;
        if (i < hi) {
            ureg[j] = csrtmp[i];
            atomicAdd(&h[ureg[j] >> 17], 1);
        }
    }
    __syncthreads();
    int v = 0;
    if (t < 256) { v = h[t]; sdata[t] = v; }
    __syncthreads();
    for (int off = 1; off < 256; off <<= 1) {
        int tmp = 0;
        if (t < 256 && t >= off) tmp = sdata[t - off];
        __syncthreads();
        if (t < 256) sdata[t] += tmp;
        __syncthreads();
    }
    if (t < 256) {
        int ex = sdata[t] - v;
        int node = b * 256 + t;
        if (node < NN) { start[node] = lo + ex; deg[node] = v; }
        h[t] = ex;
    }
    __syncthreads();
#pragma unroll
    for (int j = 0; j < 10; ++j) {
        int i = lo + t + j * 1024;
        if (i < hi) {
            unsigned u = ureg[j];
            int r = atomicAdd(&h[u >> 17], 1);   // LDS atomic
            csrsrc[lo + r] = (int)(u & 0x1FFFFu);
        }
    }
}

// ===== gather core: 8 lanes/node, fp8 rows, packed-f16 accumulate =====
// Software-pipelined index load: iteration i consumes myIdx loaded in i-1;
// the next index load issues right after the shfl so its latency hides under
// the 8 feat loads + decode. Clamp semantics identical to round 25/31.
__device__ inline float4 gather_core(const int* __restrict__ csrsrc,
                                     const unsigned* __restrict__ feat8,
                                     int s, int e, unsigned c)
{
    __half2 zero2 = __float2half2_rn(0.f);
    __half2 p0a = zero2, p0b = zero2, p1a = zero2, p1b = zero2;
    __half2 p2a = zero2, p2b = zero2, p3a = zero2, p3b = zero2;
    float4 corr = make_float4(0.f, 0.f, 0.f, 0.f);
    int idx0 = s + (int)c;
    idx0 = idx0 < e ? idx0 : e - 1;
    int myIdx = csrsrc[idx0];                      // prologue index load
    for (int i = s; i < e; i += 8) {
        unsigned off[8];
#pragma unroll
        for (int q = 0; q < 8; ++q)
            off[q] = (unsigned)__shfl(myIdx, q, 8) * 8u + c;
        int nidx = i + 8 + (int)c;                 // prefetch next iter's index
        nidx = nidx < e ? nidx : e - 1;            // clamped: always in-bounds
        int nextIdx = csrsrc[nidx];
        unsigned vv[8];
#pragma unroll
        for (int q = 0; q < 8; ++q) vv[q] = feat8[off[q]];
#pragma unroll
        for (int q = 0; q < 8; ++q) {
            unsigned w = vv[q];
            unsigned p01 = __builtin_amdgcn_perm(0u, w, 0x04010400u);
            unsigned p23 = __builtin_amdgcn_perm(0u, w, 0x04030402u);
            unsigned h01 = (p01 << 7) + ((p01 & 0x00800080u) << 7) + 0x20002000u;
            unsigned h23 = (p23 << 7) + ((p23 & 0x00800080u) << 7) + 0x20002000u;
            __half2 a01 = __builtin_bit_cast(__half2, h01);
            __half2 a23 = __builtin_bit_cast(__half2, h23);
            if ((q & 3) == 0) { p0a = __hadd2(p0a, a01); p0b = __hadd2(p0b, a23); }
            if ((q & 3) == 1) { p1a = __hadd2(p1a, a01); p1b = __hadd2(p1b, a23); }
            if ((q & 3) == 2) { p2a = __hadd2(p2a, a01); p2b = __hadd2(p2b, a23); }
            if ((q & 3) == 3) { p3a = __hadd2(p3a, a01); p3b = __hadd2(p3b, a23); }
        }
        if (i + 8 > e) {                           // final partial: exact correction
            float k = (float)(i + 8 - e);          // duplicates of csrsrc[e-1]
            unsigned w = vv[7];                    // q=7 is always clamped here
            corr.x = k * dec8(w & 0xFFu);
            corr.y = k * dec8((w >> 8) & 0xFFu);
            corr.z = k * dec8((w >> 16) & 0xFFu);
            corr.w = k * dec8(w >> 24);
        }
        myIdx = nextIdx;
    }
    float2 f0a = __half22float2(p0a), f1a = __half22float2(p1a);
    float2 f2a = __half22float2(p2a), f3a = __half22float2(p3a);
    float2 f0b = __half22float2(p0b), f1b = __half22float2(p1b);
    float2 f2b = __half22float2(p2b), f3b = __half22float2(p3b);
    float4 r;
    r.x = f0a.x + f1a.x + f2a.x + f3a.x - corr.x;
    r.y = f0a.y + f1a.y + f2a.y + f3a.y - corr.y;
    r.z = f0b.x + f1b.x + f2b.x + f3b.x - corr.z;
    r.w = f0b.y + f1b.y + f2b.y + f3b.y - corr.w;
    return r;
}

// ===== fused layer 1 (sequential nodes, no block barrier, bf16 root) =====
__global__ __launch_bounds__(256) void fused1_kernel(
    const int* __restrict__ start, const int* __restrict__ deg,
    const int* __restrict__ csrsrc, const unsigned* __restrict__ feat8,
    const unsigned short* __restrict__ xrbf, const float* __restrict__ b1,
    const float* __restrict__ W2l, const float* __restrict__ W2r,
    unsigned* __restrict__ hlf8u, unsigned short* __restrict__ hrbf)
{
    __shared__ float hs[32][HSS];
    int tid = blockIdx.x * 256 + threadIdx.x;   // grid exact: NN*8 threads
    int g = tid >> 3;
    unsigned c = threadIdx.x & 7;
    int nl = threadIdx.x >> 3;                  // 0..31

    int s = start[g];
    int dg = deg[g];
    int e = s + dg;
    float4 r = gather_core(csrsrc, feat8, s, e, c);

    float inv = 1.0f / fmaxf((float)dg, 1.0f);
    uint2 rt = *reinterpret_cast<const uint2*>(xrbf + (size_t)g * DH + c * 4);
    const float4 bb = *reinterpret_cast<const float4*>(b1 + c * 4);
    float4 o;
    o.x = fmaf(r.x, inv, bb.x + bflo(rt.x));
    o.y = fmaf(r.y, inv, bb.y + bfhi(rt.x));
    o.z = fmaf(r.z, inv, bb.z + bflo(rt.y));
    o.w = fmaf(r.w, inv, bb.w + bfhi(rt.y));

    float ss = o.x*o.x + o.y*o.y + o.z*o.z + o.w*o.w;
    ss += __shfl_xor(ss, 1);
    ss += __shfl_xor(ss, 2);
    ss += __shfl_xor(ss, 4);
    float rn = 1.0f / fmaxf(sqrtf(ss), 1e-12f);
    float4 h;
    h.x = tanhf(o.x * rn); h.y = tanhf(o.y * rn);
    h.z = tanhf(o.z * rn); h.w = tanhf(o.w * rn);
    *reinterpret_cast<float4*>(&hs[nl][c * 4]) = h;
    // no __syncthreads: hs[nl] written/read only by this 8-lane group (same wave)

    float al[4] = {0.f, 0.f, 0.f, 0.f};
    float ar[4] = {0.f, 0.f, 0.f, 0.f};
#pragma unroll
    for (int k4 = 0; k4 < 8; ++k4) {
        float4 hv = *reinterpret_cast<const float4*>(&hs[nl][k4 * 4]);
        float hk[4] = {hv.x, hv.y, hv.z, hv.w};
#pragma unroll
        for (int kk = 0; kk < 4; ++kk) {
            const float4* wl4 = reinterpret_cast<const float4*>(W2l + (k4*4+kk) * DH + c * 4);
            const float4* wr4 = reinterpret_cast<const float4*>(W2r + (k4*4+kk) * DH + c * 4);
            float4 wl = wl4[0], wr = wr4[0];
            al[0] = fmaf(hk[kk], wl.x, al[0]);
            al[1] = fmaf(hk[kk], wl.y, al[1]);
            al[2] = fmaf(hk[kk], wl.z, al[2]);
            al[3] = fmaf(hk[kk], wl.w, al[3]);
            ar[0] = fmaf(hk[kk], wr.x, ar[0]);
            ar[1] = fmaf(hk[kk], wr.y, ar[1]);
            ar[2] = fmaf(hk[kk], wr.z, ar[2]);
            ar[3] = fmaf(hk[kk], wr.w, ar[3]);
        }
    }
    hlf8u[(size_t)g * 8 + c] = f2fp8(al[0]) | (f2fp8(al[1]) << 8) |
                               (f2fp8(al[2]) << 16) | (f2fp8(al[3]) << 24);
    unsigned w0 = (unsigned)f2bf(ar[0]) | ((unsigned)f2bf(ar[1]) << 16);
    unsigned w1 = (unsigned)f2bf(ar[2]) | ((unsigned)f2bf(ar[3]) << 16);
    *reinterpret_cast<uint2*>(hrbf + (size_t)g * DH + c * 4) = make_uint2(w0, w1);
}

// ===== fused layer 2 (sequential nodes, no block barrier, bf16 root) =====
__global__ __launch_bounds__(256) void fused2_kernel(
    const int* __restrict__ start, const int* __restrict__ deg,
    const int* __restrict__ csrsrc, const unsigned* __restrict__ feat8,
    const unsigned short* __restrict__ hrbf, const float* __restrict__ b2,
    const float* __restrict__ Wc, const float* __restrict__ bc,
    float* __restrict__ h2out, float* __restrict__ outp)
{
    __shared__ float hs[32][HSS];
    int tid = blockIdx.x * 256 + threadIdx.x;
    int g = tid >> 3;
    unsigned c = threadIdx.x & 7;
    int nl = threadIdx.x >> 3;

    int s = start[g];
    int dg = deg[g];
    int e = s + dg;
    float4 r = gather_core(csrsrc, feat8, s, e, c);

    float inv = 1.0f / fmaxf((float)dg, 1.0f);
    uint2 rt = *reinterpret_cast<const uint2*>(hrbf + (size_t)g * DH + c * 4);
    const float4 bb = *reinterpret_cast<const float4*>(b2 + c * 4);
    float4 o;
    o.x = fmaf(r.x, inv, bb.x + bflo(rt.x));
    o.y = fmaf(r.y, inv, bb.y + bfhi(rt.x));
    o.z = fmaf(r.z, inv, bb.z + bflo(rt.y));
    o.w = fmaf(r.w, inv, bb.w + bfhi(rt.y));

    float ss = o.x*o.x + o.y*o.y + o.z*o.z + o.w*o.w;
    ss += __shfl_xor(ss, 1);
    ss += __shfl_xor(ss, 2);
    ss += __shfl_xor(ss, 4);
    float rn = 1.0f / fmaxf(sqrtf(ss), 1e-12f);
    float4 h;
    h.x = tanhf(o.x * rn); h.y = tanhf(o.y * rn);
    h.z = tanhf(o.z * rn); h.w = tanhf(o.w * rn);
    *reinterpret_cast<float4*>(&hs[nl][c * 4]) = h;
    *reinterpret_cast<float4*>(h2out + (size_t)g * DH + c * 4) = h;
    // no __syncthreads: group-local LDS row, same wave

    // classifier: lanes 0-3 of each 8-lane group compute 5 logits each
    if (c < 4) {
        float z[5];
#pragma unroll
        for (int q = 0; q < 5; ++q) z[q] = bc[c * 5 + q];
#pragma unroll
        for (int k4 = 0; k4 < 8; ++k4) {
            float4 hv = *reinterpret_cast<const float4*>(&hs[nl][k4 * 4]);
            float hk[4] = {hv.x, hv.y, hv.z, hv.w};
#pragma unroll
            for (int kk = 0; kk < 4; ++kk) {
                const float* wc = Wc + (k4*4+kk) * DOUT + c * 5;
#pragma unroll
                for (int q = 0; q < 5; ++q) z[q] = fmaf(hk[kk], wc[q], z[q]);
            }
        }
        float m = z[0];
#pragma unroll
        for (int q = 1; q < 5; ++q) m = fmaxf(m, z[q]);
        m = fmaxf(m, __shfl_xor(m, 1));
        m = fmaxf(m, __shfl_xor(m, 2));
        float sum = 0.f;
#pragma unroll
        for (int q = 0; q < 5; ++q) sum += expf(z[q] - m);
        sum += __shfl_xor(sum, 1);
        sum += __shfl_xor(sum, 2);
        float lse = m + logf(sum);
        float* orow = outp + (size_t)g * DOUT + c * 5;
#pragma unroll
        for (int q = 0; q < 5; ++q) orow[q] = z[q] - lse;
    }
}

extern "C" void kernel_launch(void* const* d_in, const int* in_sizes, int n_in,
                              void* d_out, int out_size, void* d_ws, size_t ws_size,
                              hipStream_t stream) {
    const float* x   = (const float*)d_in[0];
    const int*   ei  = (const int*)d_in[1];
    const float* W1l = (const float*)d_in[2];
    const float* b1  = (const float*)d_in[3];
    const float* W1r = (const float*)d_in[4];
    const float* W2l = (const float*)d_in[5];
    const float* b2  = (const float*)d_in[6];
    const float* W2r = (const float*)d_in[7];
    const float* Wc  = (const float*)d_in[8];
    const float* bc  = (const float*)d_in[9];

    float* outp = (float*)d_out;                          // [NN, 20]
    float* hout = outp + (size_t)NN * DOUT;               // [NN, 32]

    // workspace layout
    unsigned char* xlf8 = (unsigned char*)d_ws;           // NN*DH fp8 (3.2 MB)
    unsigned char* hlf8 = xlf8 + (size_t)NN * DH;         // NN*DH fp8 (3.2 MB)
    unsigned short* xrbf = (unsigned short*)(hlf8 + (size_t)NN * DH); // NN*DH bf16 (also hr)
    unsigned* csrtmp = (unsigned*)(xrbf + (size_t)NN * DH); // NB*BSTRIDE u32 (gapped)
    int* csrsrc    = (int*)(csrtmp + (size_t)NB * BSTRIDE); // NB*BSTRIDE (gapped)
    int* start     = csrsrc + (size_t)NB * BSTRIDE;       // NN
    int* deg       = start + NN;                          // NN
    int* gcur      = deg + NN;                            // NB

    const int lin1Blocks  = (NN + NPB - 1) / NPB;         // 1563
    const int fusedBlocks = (NN * 8) / 256;               // 3125 exact

    lin1_kernel<<<lin1Blocks, 256, 0, stream>>>(x, W1l, W1r, xlf8, xrbf, gcur);

    scatterR_kernel<<<NBLK, 1024, 0, stream>>>(ei, gcur, csrtmp);
    regroupD_kernel<<<NBUSE, 1024, 0, stream>>>(csrtmp, gcur, csrsrc, start, deg);

    fused1_kernel<<<fusedBlocks, 256, 0, stream>>>(start, deg, csrsrc,
        (const unsigned*)xlf8, xrbf, b1, W2l, W2r, (unsigned*)hlf8, xrbf);

    fused2_kernel<<<fusedBlocks, 256, 0, stream>>>(start, deg, csrsrc,
        (const unsigned*)hlf8, xrbf, b2, Wc, bc, hout, outp);
}

// Round 35
// 149.192 us; speedup vs baseline: 1.0289x; 1.0001x over previous
//
#include <hip/hip_runtime.h>
#include <hip/hip_fp16.h>
#include <cmath>

constexpr int NN   = 100000;
constexpr int NE   = 3200000;
constexpr int DIN  = 128;
constexpr int DH   = 32;
constexpr int DOUT = 20;

constexpr int NB    = 392;                 // coarse buckets: dst>>8 -> 0..390 (+1 pad)
constexpr int NBUSE = (NN + 255) / 256;    // 391 buckets actually used
constexpr int NBLK  = 256;                 // scatter blocks
constexpr int SLICE = NE / NBLK;           // 12500 edges per block (exact)
constexpr int BSTRIDE = 10240;             // per-bucket region (mean 8192, 22 sigma)

constexpr int NPB = 64;                    // nodes per lin1 block
constexpr int XSB = 136;                   // bf16 LDS row stride (16B-aligned, 2-way banks)
constexpr int HSS = 36;                    // fused hs row stride (16B-aligned)

typedef __attribute__((ext_vector_type(8))) short short8v;   // 8 bf16 (4 VGPRs)
typedef __attribute__((ext_vector_type(4))) float f32x4;     // MFMA accumulator

__device__ inline unsigned short f2bf(float f) {           // RNE float->bf16
    unsigned u = __builtin_bit_cast(unsigned, f);
    unsigned r = 0x7FFFu + ((u >> 16) & 1u);
    return (unsigned short)((u + r) >> 16);
}
__device__ inline float bflo(unsigned u) {                 // low bf16 -> float
    return __builtin_bit_cast(float, u << 16);
}
__device__ inline float bfhi(unsigned u) {                 // high bf16 -> float
    return __builtin_bit_cast(float, u & 0xFFFF0000u);
}

// ---- manual fp8 e4m3fn codec (extended-low: e=0 decodes as 2^-7*(1+m/8)) ----
__device__ inline unsigned f2fp8(float f) {                // RNE float->fp8 byte
    unsigned u = __builtin_bit_cast(unsigned, f);
    unsigned s = (u >> 24) & 0x80u;
    unsigned au = u & 0x7fffffffu;
    if (au > 0x43E00000u) au = 0x43E00000u;                // clamp to 448
    unsigned u2 = au + 0x7FFFFu + ((au >> 20) & 1u);       // RNE on dropped 20 bits
    int em = (int)(u2 >> 20) - (120 << 3);                 // (E-120)<<3 | m
    em = em < 0 ? 0 : (em > 0x7E ? 0x7E : em);
    return s | (unsigned)em;
}
__device__ inline float dec8(unsigned b) {                 // fp8 byte -> float
    unsigned r = ((b & 0x80u) << 24) | (((b & 0x7fu) << 20) + 0x3C000000u);
    return __builtin_bit_cast(float, r);
}

// ------------- layer-1 projections via MFMA: xl(fp8)=x@W1l, xr(bf16)=x@W1r -------------
// blocks 0/1 additionally initialize the bucket cursors (ordered before scatterR
// by the kernel boundary on the stream).
__global__ __launch_bounds__(256, 4) void lin1_kernel(
    const float* __restrict__ x, const float* __restrict__ Wl,
    const float* __restrict__ Wr, unsigned char* __restrict__ xlf8,
    unsigned short* __restrict__ xrbf, int* __restrict__ gcur)
{
    __shared__ unsigned short xs[NPB * XSB];   // 17408 B
    int t = threadIdx.x;
    if (blockIdx.x < 2) {
        int i = blockIdx.x * 256 + t;
        if (i < NB) gcur[i] = i * BSTRIDE;
    }
    int nodeBase = blockIdx.x * NPB;

    const float4* x4 = reinterpret_cast<const float4*>(x) + (size_t)nodeBase * (DIN / 4);
    for (int i = t; i < NPB * (DIN / 4); i += 256) {
        int n = i >> 5, c = i & 31;
        float4 v = make_float4(0.f, 0.f, 0.f, 0.f);
        if (nodeBase + n < NN) v = x4[i];
        unsigned lo = (unsigned)f2bf(v.x) | ((unsigned)f2bf(v.y) << 16);
        unsigned hi = (unsigned)f2bf(v.z) | ((unsigned)f2bf(v.w) << 16);
        *reinterpret_cast<uint2*>(&xs[n * XSB + c * 4]) = make_uint2(lo, hi);
    }
    __syncthreads();

    int wv   = t >> 6;                 // 0..3
    int lane = t & 63;
    const float* W = (wv & 2) ? Wr : Wl;
    int jbase = (wv & 1) * 16;
    int ncol  = jbase + (lane & 15);   // B: col = lane&15
    int krow  = (lane >> 4) * 8;       // B/A: k-chunk = (lane>>4)*8

    short8v bfrag[4];
#pragma unroll
    for (int ks = 0; ks < 4; ++ks) {
        const float* wp = W + (ks * 32 + krow) * DH + ncol;
        short8v f;
#pragma unroll
        for (int e = 0; e < 8; ++e) f[e] = (short)f2bf(wp[e * DH]);
        bfrag[ks] = f;
    }

    f32x4 acc[4];
#pragma unroll
    for (int m = 0; m < 4; ++m) acc[m] = f32x4{0.f, 0.f, 0.f, 0.f};

#pragma unroll
    for (int m = 0; m < 4; ++m) {
        int row = m * 16 + (lane & 15);
#pragma unroll
        for (int ks = 0; ks < 4; ++ks) {
            short8v a = *reinterpret_cast<const short8v*>(&xs[row * XSB + ks * 32 + krow]);
            acc[m] = __builtin_amdgcn_mfma_f32_16x16x32_bf16(a, bfrag[ks], acc[m], 0, 0, 0);
        }
    }

#pragma unroll
    for (int m = 0; m < 4; ++m) {
        int rbase = m * 16 + (lane >> 4) * 4;
#pragma unroll
        for (int r = 0; r < 4; ++r) {
            int node = nodeBase + rbase + r;
            if (node < NN) {
                float v = acc[m][r];
                if (wv & 2) xrbf[(size_t)node * DH + ncol] = f2bf(v);
                else        xlf8[(size_t)node * DH + ncol] = (unsigned char)f2fp8(v);
            }
        }
    }
}

// ------- reservation multisplit: LDS count -> reserve region -> scatter -------
// Pass-1 dst values are register-cached (13/thread) so pass 2 reads only src.
__global__ __launch_bounds__(1024) void scatterR_kernel(
    const int* __restrict__ ei, int* __restrict__ gcur,
    unsigned* __restrict__ csrtmp)
{
    __shared__ int cnt[NB];
    __shared__ int wb[NB];
    int blk = blockIdx.x, t = threadIdx.x;
    for (int i = t; i < NB; i += 1024) cnt[i] = 0;
    __syncthreads();
    int base = blk * SLICE;
    int dreg[13];
#pragma unroll
    for (int j = 0; j < 13; ++j) {
        int k = t + j * 1024;
        if (k < SLICE) {
            dreg[j] = ei[NE + base + k];
            atomicAdd(&cnt[dreg[j] >> 8], 1);                // pass 1: count
        }
    }
    __syncthreads();
    for (int i = t; i < NB; i += 1024) {
        int n = cnt[i];
        wb[i] = n ? atomicAdd(&gcur[i], n) : 0;              // reserve region
        cnt[i] = 0;                                          // reuse as cursor
    }
    __syncthreads();
#pragma unroll
    for (int j = 0; j < 13; ++j) {                           // pass 2: scatter
        int k = t + j * 1024;
        if (k < SLICE) {
            int dst = dreg[j];
            int src = ei[base + k];
            int b = dst >> 8;
            int r = atomicAdd(&cnt[b], 1);                   // LDS atomic
            csrtmp[wb[b] + r] = ((unsigned)(dst & 255) << 17) | (unsigned)src;
        }
    }
}

// ------- regroup within bucket -> csrsrc (gapped layout) + start + deg -------
// csrtmp words register-cached (<=10/thread): single global read per word.
__global__ __launch_bounds__(1024) void regroupD_kernel(
    const unsigned* __restrict__ csrtmp, const int* __restrict__ gcur,
    int* __restrict__ csrsrc, int* __restrict__ start, int* __restrict__ deg)
{
    __shared__ int h[256];
    __shared__ int sdata[256];
    int b = blockIdx.x, t = threadIdx.x;
    int lo = b * BSTRIDE, hi = gcur[b];
    if (t < 256) h[t] = 0;
    __syncthreads();
    unsigned ureg[10];
#pragma unroll
    for (int j = 0; j < 10; ++j) {
        int i = lo + t + j * 1024;
        if (i < hi) {
            ureg[j] = csrtmp[i];
            atomicAdd(&h[ureg[j] >> 17], 1);
        }
    }
    __syncthreads();
    int v = 0;
    if (t < 256) { v = h[t]; sdata[t] = v; }
    __syncthreads();
    for (int off = 1; off < 256; off <<= 1) {
        int tmp = 0;
        if (t < 256 && t >= off) tmp = sdata[t - off];
        __syncthreads();
        if (t < 256) sdata[t] += tmp;
        __syncthreads();
    }
    if (t < 256) {
        int ex = sdata[t] - v;
        int node = b * 256 + t;
        if (node < NN) { start[node] = lo + ex; deg[node] = v; }
        h[t] = ex;
    }
    __syncthreads();
#pragma unroll
    for (int j = 0; j < 10; ++j) {
        int i = lo + t + j * 1024;
        if (i < hi) {
            unsigned u = ureg[j];
            int r = atomicAdd(&h[u >> 17], 1);   // LDS atomic
            csrsrc[lo + r] = (int)(u & 0x1FFFFu);
        }
    }
}

// ===== gather core: 8 lanes/node, fp8 rows, packed-f16 accumulate, 16-wide =====
// Each trip processes 16 neighbors: lane c loads two clamped indices, 16 shfl
// distribute, 16 feat loads in flight before decode (2x MLP vs 8-wide).
// Pipelined index pair; exact tail correction via duplicated last neighbor.
__device__ inline float4 gather_core(const int* __restrict__ csrsrc,
                                      const unsigned* __restrict__ feat8,
                                      int s, int e, unsigned c)
{
    __half2 zero2 = __float2half2_rn(0.f);
    __half2 p0a = zero2, p0b = zero2, p1a = zero2, p1b = zero2;
    __half2 p2a = zero2, p2b = zero2, p3a = zero2, p3b = zero2;
    float4 corr = make_float4(0.f, 0.f, 0.f, 0.f);
    int ia = s + (int)c;        ia = ia < e ? ia : e - 1;
    int ib = s + 8 + (int)c;    ib = ib < e ? ib : e - 1;
    int idxA = csrsrc[ia];                          // prologue index pair
    int idxB = csrsrc[ib];
    for (int i = s; i < e; i += 16) {
        unsigned off[16];
#pragma unroll
        for (int q = 0; q < 8; ++q)
            off[q] = (unsigned)__shfl(idxA, q, 8) * 8u + c;
#pragma unroll
        for (int q = 0; q < 8; ++q)
            off[8 + q] = (unsigned)__shfl(idxB, q, 8) * 8u + c;
        int na = i + 16 + (int)c;      na = na < e ? na : e - 1;   // prefetch next pair
        int nb = i + 24 + (int)c;      nb = nb < e ? nb : e - 1;
        int nextA = csrsrc[na];
        int nextB = csrsrc[nb];
        unsigned vv[16];
#pragma unroll
        for (int q = 0; q < 16; ++q) vv[q] = feat8[off[q]];
#pragma unroll
        for (int q = 0; q < 16; ++q) {
            unsigned w = vv[q];
            unsigned p01 = __builtin_amdgcn_perm(0u, w, 0x04010400u);
            unsigned p23 = __builtin_amdgcn_perm(0u, w, 0x04030402u);
            unsigned h01 = (p01 << 7) + ((p01 & 0x00800080u) << 7) + 0x20002000u;
            unsigned h23 = (p23 << 7) + ((p23 & 0x00800080u) << 7) + 0x20002000u;
            __half2 a01 = __builtin_bit_cast(__half2, h01);
            __half2 a23 = __builtin_bit_cast(__half2, h23);
            if ((q & 3) == 0) { p0a = __hadd2(p0a, a01); p0b = __hadd2(p0b, a23); }
            if ((q & 3) == 1) { p1a = __hadd2(p1a, a01); p1b = __hadd2(p1b, a23); }
            if ((q & 3) == 2) { p2a = __hadd2(p2a, a01); p2b = __hadd2(p2b, a23); }
            if ((q & 3) == 3) { p3a = __hadd2(p3a, a01); p3b = __hadd2(p3b, a23); }
        }
        if (i + 16 > e) {                           // final partial: exact correction
            float k = (float)(i + 16 - e);          // duplicates of csrsrc[e-1]
            unsigned w = vv[15];                    // q=15 is always clamped here
            corr.x = k * dec8(w & 0xFFu);
            corr.y = k * dec8((w >> 8) & 0xFFu);
            corr.z = k * dec8((w >> 16) & 0xFFu);
            corr.w = k * dec8(w >> 24);
        }
        idxA = nextA;
        idxB = nextB;
    }
    float2 f0a = __half22float2(p0a), f1a = __half22float2(p1a);
    float2 f2a = __half22float2(p2a), f3a = __half22float2(p3a);
    float2 f0b = __half22float2(p0b), f1b = __half22float2(p1b);
    float2 f2b = __half22float2(p2b), f3b = __half22float2(p3b);
    float4 r;
    r.x = f0a.x + f1a.x + f2a.x + f3a.x - corr.x;
    r.y = f0a.y + f1a.y + f2a.y + f3a.y - corr.y;
    r.z = f0b.x + f1b.x + f2b.x + f3b.x - corr.z;
    r.w = f0b.y + f1b.y + f2b.y + f3b.y - corr.w;
    return r;
}

// ===== fused layer 1 (sequential nodes, no block barrier, bf16 root) =====
__global__ __launch_bounds__(256) void fused1_kernel(
    const int* __restrict__ start, const int* __restrict__ deg,
    const int* __restrict__ csrsrc, const unsigned* __restrict__ feat8,
    const unsigned short* __restrict__ xrbf, const float* __restrict__ b1,
    const float* __restrict__ W2l, const float* __restrict__ W2r,
    unsigned* __restrict__ hlf8u, unsigned short* __restrict__ hrbf)
{
    __shared__ float hs[32][HSS];
    int tid = blockIdx.x * 256 + threadIdx.x;   // grid exact: NN*8 threads
    int g = tid >> 3;
    unsigned c = threadIdx.x & 7;
    int nl = threadIdx.x >> 3;                  // 0..31

    int s = start[g];
    int dg = deg[g];
    int e = s + dg;
    float4 r = gather_core(csrsrc, feat8, s, e, c);

    float inv = 1.0f / fmaxf((float)dg, 1.0f);
    uint2 rt = *reinterpret_cast<const uint2*>(xrbf + (size_t)g * DH + c * 4);
    const float4 bb = *reinterpret_cast<const float4*>(b1 + c * 4);
    float4 o;
    o.x = fmaf(r.x, inv, bb.x + bflo(rt.x));
    o.y = fmaf(r.y, inv, bb.y + bfhi(rt.x));
    o.z = fmaf(r.z, inv, bb.z + bflo(rt.y));
    o.w = fmaf(r.w, inv, bb.w + bfhi(rt.y));

    float ss = o.x*o.x + o.y*o.y + o.z*o.z + o.w*o.w;
    ss += __shfl_xor(ss, 1);
    ss += __shfl_xor(ss, 2);
    ss += __shfl_xor(ss, 4);
    float rn = 1.0f / fmaxf(sqrtf(ss), 1e-12f);
    float4 h;
    h.x = tanhf(o.x * rn); h.y = tanhf(o.y * rn);
    h.z = tanhf(o.z * rn); h.w = tanhf(o.w * rn);
    *reinterpret_cast<float4*>(&hs[nl][c * 4]) = h;
    // no __syncthreads: hs[nl] written/read only by this 8-lane group (same wave)

    float al[4] = {0.f, 0.f, 0.f, 0.f};
    float ar[4] = {0.f, 0.f, 0.f, 0.f};
#pragma unroll
    for (int k4 = 0; k4 < 8; ++k4) {
        float4 hv = *reinterpret_cast<const float4*>(&hs[nl][k4 * 4]);
        float hk[4] = {hv.x, hv.y, hv.z, hv.w};
#pragma unroll
        for (int kk = 0; kk < 4; ++kk) {
            const float4* wl4 = reinterpret_cast<const float4*>(W2l + (k4*4+kk) * DH + c * 4);
            const float4* wr4 = reinterpret_cast<const float4*>(W2r + (k4*4+kk) * DH + c * 4);
            float4 wl = wl4[0], wr = wr4[0];
            al[0] = fmaf(hk[kk], wl.x, al[0]);
            al[1] = fmaf(hk[kk], wl.y, al[1]);
            al[2] = fmaf(hk[kk], wl.z, al[2]);
            al[3] = fmaf(hk[kk], wl.w, al[3]);
            ar[0] = fmaf(hk[kk], wr.x, ar[0]);
            ar[1] = fmaf(hk[kk], wr.y, ar[1]);
            ar[2] = fmaf(hk[kk], wr.z, ar[2]);
            ar[3] = fmaf(hk[kk], wr.w, ar[3]);
        }
    }
    hlf8u[(size_t)g * 8 + c] = f2fp8(al[0]) | (f2fp8(al[1]) << 8) |
                               (f2fp8(al[2]) << 16) | (f2fp8(al[3]) << 24);
    unsigned w0 = (unsigned)f2bf(ar[0]) | ((unsigned)f2bf(ar[1]) << 16);
    unsigned w1 = (unsigned)f2bf(ar[2]) | ((unsigned)f2bf(ar[3]) << 16);
    *reinterpret_cast<uint2*>(hrbf + (size_t)g * DH + c * 4) = make_uint2(w0, w1);
}

// ===== fused layer 2 (sequential nodes, no block barrier, bf16 root) =====
__global__ __launch_bounds__(256) void fused2_kernel(
    const int* __restrict__ start, const int* __restrict__ deg,
    const int* __restrict__ csrsrc, const unsigned* __restrict__ feat8,
    const unsigned short* __restrict__ hrbf, const float* __restrict__ b2,
    const float* __restrict__ Wc, const float* __restrict__ bc,
    float* __restrict__ h2out, float* __restrict__ outp)
{
    __shared__ float hs[32][HSS];
    int tid = blockIdx.x * 256 + threadIdx.x;
    int g = tid >> 3;
    unsigned c = threadIdx.x & 7;
    int nl = threadIdx.x >> 3;

    int s = start[g];
    int dg = deg[g];
    int e = s + dg;
    float4 r = gather_core(csrsrc, feat8, s, e, c);

    float inv = 1.0f / fmaxf((float)dg, 1.0f);
    uint2 rt = *reinterpret_cast<const uint2*>(hrbf + (size_t)g * DH + c * 4);
    const float4 bb = *reinterpret_cast<const float4*>(b2 + c * 4);
    float4 o;
    o.x = fmaf(r.x, inv, bb.x + bflo(rt.x));
    o.y = fmaf(r.y, inv, bb.y + bfhi(rt.x));
    o.z = fmaf(r.z, inv, bb.z + bflo(rt.y));
    o.w = fmaf(r.w, inv, bb.w + bfhi(rt.y));

    float ss = o.x*o.x + o.y*o.y + o.z*o.z + o.w*o.w;
    ss += __shfl_xor(ss, 1);
    ss += __shfl_xor(ss, 2);
    ss += __shfl_xor(ss, 4);
    float rn = 1.0f / fmaxf(sqrtf(ss), 1e-12f);
    float4 h;
    h.x = tanhf(o.x * rn); h.y = tanhf(o.y * rn);
    h.z = tanhf(o.z * rn); h.w = tanhf(o.w * rn);
    *reinterpret_cast<float4*>(&hs[nl][c * 4]) = h;
    *reinterpret_cast<float4*>(h2out + (size_t)g * DH + c * 4) = h;
    // no __syncthreads: group-local LDS row, same wave

    // classifier: lanes 0-3 of each 8-lane group compute 5 logits each
    if (c < 4) {
        float z[5];
#pragma unroll
        for (int q = 0; q < 5; ++q) z[q] = bc[c * 5 + q];
#pragma unroll
        for (int k4 = 0; k4 < 8; ++k4) {
            float4 hv = *reinterpret_cast<const float4*>(&hs[nl][k4 * 4]);
            float hk[4] = {hv.x, hv.y, hv.z, hv.w};
#pragma unroll
            for (int kk = 0; kk < 4; ++kk) {
                const float* wc = Wc + (k4*4+kk) * DOUT + c * 5;
#pragma unroll
                for (int q = 0; q < 5; ++q) z[q] = fmaf(hk[kk], wc[q], z[q]);
            }
        }
        float m = z[0];
#pragma unroll
        for (int q = 1; q < 5; ++q) m = fmaxf(m, z[q]);
        m = fmaxf(m, __shfl_xor(m, 1));
        m = fmaxf(m, __shfl_xor(m, 2));
        float sum = 0.f;
#pragma unroll
        for (int q = 0; q < 5; ++q) sum += expf(z[q] - m);
        sum += __shfl_xor(sum, 1);
        sum += __shfl_xor(sum, 2);
        float lse = m + logf(sum);
        float* orow = outp + (size_t)g * DOUT + c * 5;
#pragma unroll
        for (int q = 0; q < 5; ++q) orow[q] = z[q] - lse;
    }
}

extern "C" void kernel_launch(void* const* d_in, const int* in_sizes, int n_in,
                              void* d_out, int out_size, void* d_ws, size_t ws_size,
                              hipStream_t stream) {
    const float* x   = (const float*)d_in[0];
    const int*   ei  = (const int*)d_in[1];
    const float* W1l = (const float*)d_in[2];
    const float* b1  = (const float*)d_in[3];
    const float* W1r = (const float*)d_in[4];
    const float* W2l = (const float*)d_in[5];
    const float* b2  = (const float*)d_in[6];
    const float* W2r = (const float*)d_in[7];
    const float* Wc  = (const float*)d_in[8];
    const float* bc  = (const float*)d_in[9];

    float* outp = (float*)d_out;                          // [NN, 20]
    float* hout = outp + (size_t)NN * DOUT;               // [NN, 32]

    // workspace layout
    unsigned char* xlf8 = (unsigned char*)d_ws;           // NN*DH fp8 (3.2 MB)
    unsigned char* hlf8 = xlf8 + (size_t)NN * DH;         // NN*DH fp8 (3.2 MB)
    unsigned short* xrbf = (unsigned short*)(hlf8 + (size_t)NN * DH); // NN*DH bf16 (also hr)
    unsigned* csrtmp = (unsigned*)(xrbf + (size_t)NN * DH); // NB*BSTRIDE u32 (gapped)
    int* csrsrc    = (int*)(csrtmp + (size_t)NB * BSTRIDE); // NB*BSTRIDE (gapped)
    int* start     = csrsrc + (size_t)NB * BSTRIDE;       // NN
    int* deg       = start + NN;                          // NN
    int* gcur      = deg + NN;                            // NB

    const int lin1Blocks  = (NN + NPB - 1) / NPB;         // 1563
    const int fusedBlocks = (NN * 8) / 256;               // 3125 exact

    lin1_kernel<<<lin1Blocks, 256, 0, stream>>>(x, W1l, W1r, xlf8, xrbf, gcur);

    scatterR_kernel<<<NBLK, 1024, 0, stream>>>(ei, gcur, csrtmp);
    regroupD_kernel<<<NBUSE, 1024, 0, stream>>>(csrtmp, gcur, csrsrc, start, deg);

    fused1_kernel<<<fusedBlocks, 256, 0, stream>>>(start, deg, csrsrc,
        (const unsigned*)xlf8, xrbf, b1, W2l, W2r, (unsigned*)hlf8, xrbf);

    fused2_kernel<<<fusedBlocks, 256, 0, stream>>>(start, deg, csrsrc,
        (const unsigned*)hlf8, xrbf, b2, Wc, bc, hout, outp);
}